// Round 4
// baseline (418.409 us; speedup 1.0000x reference)
//
#include <hip/hip_runtime.h>
#include <hip/hip_fp16.h>
#include <math.h>

#define Nn 10000
#define Ee 320000
#define EE 330000        // E + N self loops
#define INF_ 256
#define NH 4
#define OUTC 128
#define F1 512
#define F2 512
#define SLOPE 0.2f
#define STRIDE 80        // ELL row capacity (max in-degree ~56; P(overflow)~1e-13)
#define LDK 40
#define NT 256
#define GRID_MAX 1024
#define MT 157           // ceil(Nn/64)
#define GEMM_TILES (MT * NH)      // 628
#define PASS_VB ((Nn / 16) * NH)  // 2500
#define SMEM_BYTES (192 * LDK * 2)   // As(64*LDK) + Bs(128*LDK) halves = 15360 B

static __device__ __forceinline__ float lrelu(float x) { return fmaxf(x, SLOPE * x); }

using frag_ab = __attribute__((ext_vector_type(8))) _Float16;
using frag_c  = __attribute__((ext_vector_type(4))) float;

struct Params {
    const float* x; const int* ei;
    const float* W1; const float* a_src1; const float* a_dst1; const float* b1;
    const float* W2; const float* a_src2; const float* a_dst2; const float* b2;
    float* out;
    int* counts; int* csr; int* bar;
    _Float16* hh; _Float16* aggh; _Float16* w1t; _Float16* w2t; _Float16* tmp;
    float* as1; float* ad1; float* as2; float* ad2;
};

// ---- device-scope grid barrier: per-phase arrival counter (zeroed by host memset) ----
// acq_rel RMW at AGENT scope publishes prior writes (incl. plain stores, ordered in
// by the preceding __syncthreads); the acquire load invalidates vector L1 so the
// whole block's subsequent reads are fresh. Deadlock-free: grid <= queried
// co-resident capacity (host gates the launch on hipOccupancyMaxActiveBlocks...).
static __device__ __forceinline__ void gbar(int* bar, int ph) {
    __syncthreads();
    if (threadIdx.x == 0) {
        __hip_atomic_fetch_add(&bar[ph], 1, __ATOMIC_ACQ_REL, __HIP_MEMORY_SCOPE_AGENT);
        while (__hip_atomic_load(&bar[ph], __ATOMIC_ACQUIRE, __HIP_MEMORY_SCOPE_AGENT) <
               (int)gridDim.x)
            __builtin_amdgcn_s_sleep(1);
    }
    __syncthreads();
}

// ---------------- phase 0: zero degree counters + W1/W2 -> fp16 transposes ----------------
static __device__ void prep0(const Params& p, int gstride) {
    int gt = blockIdx.x * NT + threadIdx.x;
    for (int i = gt; i < Nn; i += gstride) p.counts[i] = 0;
    for (int i = gt; i < F1 * INF_; i += gstride) {    // w1t[n][k] = W1[k][n]
        int n = i >> 8, k = i & 255;
        p.w1t[i] = (_Float16)p.W1[(size_t)k * F1 + n];
    }
    for (int i = gt; i < F2 * F1; i += gstride) {      // w2t[n][k] = W2[k][n]
        int n = i >> 9, k = i & 511;
        p.w2t[i] = (_Float16)p.W2[(size_t)k * F2 + n];
    }
}

// ---------------- ELL scatter (self-counting, no scan) ----------------
static __device__ void scatter_edges(const Params& p, int bi, int nb) {
    for (int e = bi * NT + threadIdx.x; e < EE; e += nb * NT) {
        int src, dst;
        if (e < Ee) { src = p.ei[e]; dst = p.ei[Ee + e]; }
        else        { src = e - Ee; dst = e - Ee; }
        int slot = atomicAdd(&p.counts[dst], 1);
        if (slot < STRIDE) p.csr[dst * STRIDE + slot] = src;
    }
}

// ---------------- MFMA fp16 GEMM tile + fused alpha dots (head-major alpha out) ----------------
// AF32: A is fp32 (layer 1 reads x directly, converts in-register during staging).
template <bool AF32>
static __device__ void gemm_tile(const _Float16* __restrict__ Ah,
                                 const float* __restrict__ Af,
                                 const _Float16* __restrict__ BT,
                                 _Float16* __restrict__ C,
                                 const float* __restrict__ a_src,
                                 const float* __restrict__ a_dst,
                                 float* __restrict__ as_out,
                                 float* __restrict__ ad_out,
                                 int K, int bmi, int head,
                                 _Float16* As, _Float16* Bs) {
    const int tid = threadIdx.x;
    const int wave = tid >> 6, lane = tid & 63;
    const int q = lane >> 4, ml = lane & 15;
    const int bm = bmi * 64, bn = head * 128;
    const int srow = tid >> 2, scol = (tid & 3) * 8;

    frag_c acc[8];
#pragma unroll
    for (int f = 0; f < 8; f++)
#pragma unroll
        for (int r = 0; r < 4; r++) acc[f][r] = 0.f;

    for (int k0 = 0; k0 < K; k0 += 32) {
        int gm = bm + srow;
        frag_ab av;
        if (gm < Nn) {
            if constexpr (AF32) {
                const float* Ap = Af + (size_t)gm * K + k0 + scol;
                float4 v0 = *(const float4*)Ap;
                float4 v1 = *(const float4*)(Ap + 4);
                av[0] = (_Float16)v0.x; av[1] = (_Float16)v0.y;
                av[2] = (_Float16)v0.z; av[3] = (_Float16)v0.w;
                av[4] = (_Float16)v1.x; av[5] = (_Float16)v1.y;
                av[6] = (_Float16)v1.z; av[7] = (_Float16)v1.w;
            } else {
                av = *(const frag_ab*)(Ah + (size_t)gm * K + k0 + scol);
            }
        } else {
#pragma unroll
            for (int j = 0; j < 8; j++) av[j] = (_Float16)0.f;
        }
        __syncthreads();   // guard As/Bs against previous iteration's readers
        *(frag_ab*)&As[srow * LDK + scol] = av;
        *(frag_ab*)&Bs[srow * LDK + scol] =
            *(const frag_ab*)(BT + (size_t)(bn + srow) * K + k0 + scol);
        *(frag_ab*)&Bs[(64 + srow) * LDK + scol] =
            *(const frag_ab*)(BT + (size_t)(bn + 64 + srow) * K + k0 + scol);
        __syncthreads();
        frag_ab a = *(frag_ab*)&As[(wave * 16 + ml) * LDK + q * 8];
#pragma unroll
        for (int f = 0; f < 8; f++) {
            frag_ab b = *(frag_ab*)&Bs[(f * 16 + ml) * LDK + q * 8];
            acc[f] = __builtin_amdgcn_mfma_f32_16x16x32_f16(a, b, acc[f], 0, 0, 0);
        }
    }
    __syncthreads();
    float asum[4] = {}, dsum[4] = {};
#pragma unroll
    for (int f = 0; f < 8; f++) {
        int cl = f * 16 + ml;
        int col = bn + cl;
        float sa = a_src[head * 128 + cl];
        float da = a_dst[head * 128 + cl];
#pragma unroll
        for (int r = 0; r < 4; r++) {
            int row = bm + wave * 16 + q * 4 + r;
            if (row < Nn) C[(size_t)row * (NH * 128) + col] = (_Float16)acc[f][r];
            asum[r] += acc[f][r] * sa;
            dsum[r] += acc[f][r] * da;
        }
    }
#pragma unroll
    for (int r = 0; r < 4; r++) {
#pragma unroll
        for (int off = 1; off < 16; off <<= 1) {
            asum[r] += __shfl_xor(asum[r], off);
            dsum[r] += __shfl_xor(dsum[r], off);
        }
    }
    if (ml == 0) {
#pragma unroll
        for (int r = 0; r < 4; r++) {
            int row = bm + wave * 16 + q * 4 + r;
            if (row < Nn) {
                as_out[(size_t)head * Nn + row] = asum[r];
                ad_out[(size_t)head * Nn + row] = dsum[r];
            }
        }
    }
}

// ---------------- fused softmax + aggregation (quarter-wave per node, head-sliced) ----------------
template <int LAYER>
static __device__ void pass_body(int vb, const int* __restrict__ counts,
                                 const int* __restrict__ csr,
                                 const float* __restrict__ as,
                                 const float* __restrict__ ad,
                                 const _Float16* __restrict__ hh,
                                 const float* __restrict__ b1,
                                 _Float16* __restrict__ outp, int2 (*ew)[84]) {
    int head = vb & 3;
    int qw = threadIdx.x >> 4;
    int l = threadIdx.x & 15;
    int n = (vb >> 2) * 16 + qw;
    int deg = counts[n]; if (deg > STRIDE) deg = STRIDE;
    int pdeg = (deg + 7) & ~7;
    const float* ash = as + (size_t)head * Nn;
    float adh = ad[(size_t)head * Nn + n];
    int base = n * STRIDE;
    float m = -1e30f;
    for (int k = l; k < pdeg; k += 16) {
        int src = 0; float v = -1e30f;
        if (k < deg) {
            src = csr[base + k];
            v = lrelu(ash[src] + adh);
        }
        ew[qw][k] = make_int2(src, __float_as_int(v));
        m = fmaxf(m, v);
    }
    m = fmaxf(m, __shfl_xor(m, 1));
    m = fmaxf(m, __shfl_xor(m, 2));
    m = fmaxf(m, __shfl_xor(m, 4));
    m = fmaxf(m, __shfl_xor(m, 8));
    float s = 0.f;
    for (int k = l; k < pdeg; k += 16) {
        float e = __expf(__int_as_float(ew[qw][k].y) - m);
        ew[qw][k].y = __float_as_int(e);
        s += e;
    }
    s += __shfl_xor(s, 1);
    s += __shfl_xor(s, 2);
    s += __shfl_xor(s, 4);
    s += __shfl_xor(s, 8);
    float inv = 1.f / (s + 1e-16f);
    int c = head * 128 + (l << 3);
    float acc[8] = {};
    for (int kk = 0; kk < pdeg; kk += 8) {
        int2 pj[8];
#pragma unroll
        for (int j = 0; j < 8; j++) pj[j] = ew[qw][kk + j];
#pragma unroll
        for (int j = 0; j < 8; j++) {
            float w = __int_as_float(pj[j].y);
            frag_ab r = *(const frag_ab*)(hh + (size_t)pj[j].x * 512 + c);
#pragma unroll
            for (int u = 0; u < 8; u++) acc[u] = fmaf((float)r[u], w, acc[u]);
        }
    }
    _Float16 oh[8];
    if constexpr (LAYER == 1) {
#pragma unroll
        for (int j = 0; j < 8; j++)
            oh[j] = (_Float16)fmaxf(acc[j] * inv + b1[c + j], 0.f);
    } else {
        float qq = 0.25f * inv;
#pragma unroll
        for (int j = 0; j < 8; j++) oh[j] = (_Float16)(acc[j] * qq);
    }
    *(float4*)&outp[(size_t)n * 512 + c] = *(float4*)oh;
}

// ---------------- final head-sum + bias ----------------
static __device__ void reduce_out(const Params& p, int gstride) {
    int gt = blockIdx.x * NT + threadIdx.x;
    for (int i = gt; i < Nn * OUTC; i += gstride) {
        int n = i >> 7, oc = i & 127;
        const _Float16* tp = p.tmp + (size_t)n * 512 + oc;
        p.out[i] = (float)tp[0] + (float)tp[128] + (float)tp[256] + (float)tp[384] + p.b2[oc];
    }
}

// ---------------- the whole pipeline as ONE persistent kernel, grid-size-agnostic ----------------
// LDS arena shared across phases (GEMM buffers and softmax edge cache never co-live;
// a grid barrier separates them): 15360 B -> >=4 blocks/CU even under a 64KB/CU budget.
__global__ __launch_bounds__(NT) void mega(Params p) {
    __shared__ __align__(16) char smem[SMEM_BYTES];
    _Float16* As = (_Float16*)smem;
    _Float16* Bs = (_Float16*)(smem + 64 * LDK * 2);
    int2 (*ew)[84] = (int2(*)[84])smem;
    const int grid = gridDim.x;
    const int gstride = grid * NT;

    // P0: counts=0, weight transposes
    prep0(p, gstride);
    gbar(p.bar, 0);

    // P1: gemm1 (fp32 A staged->fp16) || ELL edge scatter on the trailing blocks
    {
        int nscat = (grid > GEMM_TILES) ? (grid - GEMM_TILES) : (grid >> 2);
        int ngemm = grid - nscat;
        if ((int)blockIdx.x < ngemm) {
            for (int t = blockIdx.x; t < GEMM_TILES; t += ngemm)
                gemm_tile<true>(nullptr, p.x, p.w1t, p.hh, p.a_src1, p.a_dst1,
                                p.as1, p.ad1, INF_, t % MT, t / MT, As, Bs);
        } else {
            scatter_edges(p, blockIdx.x - ngemm, nscat);
        }
    }
    gbar(p.bar, 1);

    // P2: softmax+aggregate layer 1 (head = vb&3 constant per block -> XCD L2 slice)
    for (int vb = blockIdx.x; vb < PASS_VB; vb += grid)
        pass_body<1>(vb, p.counts, p.csr, p.as1, p.ad1, p.hh, p.b1, p.aggh, ew);
    gbar(p.bar, 2);

    // P3: gemm2
    for (int t = blockIdx.x; t < GEMM_TILES; t += grid)
        gemm_tile<false>(p.aggh, nullptr, p.w2t, p.hh, p.a_src2, p.a_dst2,
                         p.as2, p.ad2, F1, t % MT, t / MT, As, Bs);
    gbar(p.bar, 3);

    // P4: softmax+aggregate layer 2
    for (int vb = blockIdx.x; vb < PASS_VB; vb += grid)
        pass_body<2>(vb, p.counts, p.csr, p.as2, p.ad2, p.hh, nullptr, p.tmp, ew);
    gbar(p.bar, 4);

    // P5: head-sum + bias
    reduce_out(p, gstride);
}

// ---------------- fallback (plain launches, no barriers) ----------------
__global__ __launch_bounds__(NT) void k_p0(Params p) { prep0(p, GRID_MAX * NT); }
__global__ __launch_bounds__(NT) void k_p1(Params p) {
    __shared__ __align__(16) char smem[SMEM_BYTES];
    _Float16* As = (_Float16*)smem;
    _Float16* Bs = (_Float16*)(smem + 64 * LDK * 2);
    if (blockIdx.x < GEMM_TILES)
        gemm_tile<true>(nullptr, p.x, p.w1t, p.hh, p.a_src1, p.a_dst1, p.as1, p.ad1,
                        INF_, blockIdx.x % MT, blockIdx.x / MT, As, Bs);
    else
        scatter_edges(p, blockIdx.x - GEMM_TILES, GRID_MAX - GEMM_TILES);
}
__global__ __launch_bounds__(NT) void k_p2(Params p) {
    __shared__ int2 ew[16][84];
    for (int vb = blockIdx.x; vb < PASS_VB; vb += GRID_MAX)
        pass_body<1>(vb, p.counts, p.csr, p.as1, p.ad1, p.hh, p.b1, p.aggh, ew);
}
__global__ __launch_bounds__(NT) void k_p3(Params p) {
    __shared__ __align__(16) char smem[SMEM_BYTES];
    _Float16* As = (_Float16*)smem;
    _Float16* Bs = (_Float16*)(smem + 64 * LDK * 2);
    if (blockIdx.x < GEMM_TILES)
        gemm_tile<false>(p.aggh, nullptr, p.w2t, p.hh, p.a_src2, p.a_dst2, p.as2, p.ad2,
                         F1, blockIdx.x % MT, blockIdx.x / MT, As, Bs);
}
__global__ __launch_bounds__(NT) void k_p4(Params p) {
    __shared__ int2 ew[16][84];
    for (int vb = blockIdx.x; vb < PASS_VB; vb += GRID_MAX)
        pass_body<2>(vb, p.counts, p.csr, p.as2, p.ad2, p.hh, nullptr, p.tmp, ew);
}
__global__ __launch_bounds__(NT) void k_p5(Params p) { reduce_out(p, GRID_MAX * NT); }

extern "C" void kernel_launch(void* const* d_in, const int* in_sizes, int n_in,
                              void* d_out, int out_size, void* d_ws, size_t ws_size,
                              hipStream_t stream) {
    Params p;
    p.x      = (const float*)d_in[0];
    p.ei     = (const int*)d_in[1];
    p.W1     = (const float*)d_in[2];
    p.a_src1 = (const float*)d_in[3];
    p.a_dst1 = (const float*)d_in[4];
    p.b1     = (const float*)d_in[5];
    p.W2     = (const float*)d_in[6];
    p.a_src2 = (const float*)d_in[7];
    p.a_dst2 = (const float*)d_in[8];
    p.b2     = (const float*)d_in[9];
    p.out    = (float*)d_out;

    char* w = (char*)d_ws;
    p.tmp  = (_Float16*)w; w += (size_t)Nn * F2 * 2;
    p.hh   = (_Float16*)w; w += (size_t)Nn * F1 * 2;
    p.aggh = (_Float16*)w; w += (size_t)Nn * F1 * 2;
    p.w1t  = (_Float16*)w; w += (size_t)F1 * INF_ * 2;
    p.w2t  = (_Float16*)w; w += (size_t)F2 * F1 * 2;
    p.as1  = (float*)w;    w += (size_t)NH * Nn * 4;
    p.ad1  = (float*)w;    w += (size_t)NH * Nn * 4;
    p.as2  = (float*)w;    w += (size_t)NH * Nn * 4;
    p.ad2  = (float*)w;    w += (size_t)NH * Nn * 4;
    p.csr  = (int*)w;      w += (size_t)Nn * STRIDE * 4;
    p.counts = (int*)w;    w += (size_t)Nn * 4;
    p.bar  = (int*)w;      w += 8 * 4;

    // Gate grid size on ACTUAL queried co-residency (deadlock-free by construction).
    static int occ = -1;
    if (occ < 0) {
        int nb = 0;
        if (hipOccupancyMaxActiveBlocksPerMultiprocessor(&nb, mega, NT, 0) != hipSuccess)
            nb = 0;
        occ = nb;
    }
    int grid = occ * 256;
    if (grid > GRID_MAX) grid = GRID_MAX;

    if (grid >= 256) {
        (void)hipMemsetAsync(p.bar, 0, 8 * sizeof(int), stream);   // zero barrier counters
        mega<<<grid, NT, 0, stream>>>(p);
    } else {
        k_p0<<<GRID_MAX, NT, 0, stream>>>(p);
        k_p1<<<GRID_MAX, NT, 0, stream>>>(p);
        k_p2<<<GRID_MAX, NT, 0, stream>>>(p);
        k_p3<<<GEMM_TILES, NT, 0, stream>>>(p);
        k_p4<<<GRID_MAX, NT, 0, stream>>>(p);
        k_p5<<<GRID_MAX, NT, 0, stream>>>(p);
    }
}

// Round 5
// 199.703 us; speedup vs baseline: 2.0952x; 2.0952x over previous
//
#include <hip/hip_runtime.h>
#include <hip/hip_fp16.h>
#include <math.h>

#define Nn 10000
#define Ee 320000
#define EE 330000        // E + N self loops
#define INF_ 256
#define NH 4
#define OUTC 128
#define F1 512
#define F2 512
#define SLOPE 0.2f
#define STRIDE 80        // ELL row capacity (max in-degree ~56; P(overflow)~1e-13)
#define LDK 40
#define MT 157           // ceil(Nn/64)

#define SC_BLOCKS 1290       // ceil(EE/256)
#define TW1_BLOCKS 512       // (F1/64)*(INF_/4)
#define TW2_BLOCKS 1024      // (F2/64)*(F1/4)
#define GEMM_GRID 640        // 8 * (4 heads * 20 mhi); m = mhi*8 + (bid&7), skip m>=157

static __device__ __forceinline__ float lrelu(float x) { return fmaxf(x, SLOPE * x); }

using frag_ab = __attribute__((ext_vector_type(8))) _Float16;
using frag_c  = __attribute__((ext_vector_type(4))) float;

// ---------------- prep: ELL scatter + W1/W2 fp16 transposes (x-conv deleted) ----------------
__global__ void prep(const int* __restrict__ ei, int* counts, int* __restrict__ csr,
                     const float* __restrict__ W1, const float* __restrict__ W2,
                     _Float16* __restrict__ w1t, _Float16* __restrict__ w2t) {
    int b = blockIdx.x, t = threadIdx.x;
    if (b < SC_BLOCKS) {
        int e = b * 256 + t;
        if (e < EE) {
            int src, dst;
            if (e < Ee) { src = ei[e]; dst = ei[Ee + e]; }
            else        { src = e - Ee; dst = e - Ee; }
            int slot = atomicAdd(&counts[dst], 1);
            if (slot < STRIDE) csr[dst * STRIDE + slot] = src;
        }
    } else if (b < SC_BLOCKS + TW1_BLOCKS) {
        int bb = b - SC_BLOCKS;
        int n = (bb & 7) * 64 + (t & 63);
        int k = (bb >> 3) * 4 + (t >> 6);
        w1t[(size_t)n * INF_ + k] = (_Float16)W1[(size_t)k * F1 + n];
    } else {
        int bb = b - SC_BLOCKS - TW1_BLOCKS;
        int n = (bb & 7) * 64 + (t & 63);
        int k = (bb >> 3) * 4 + (t >> 6);
        w2t[(size_t)n * F1 + k] = (_Float16)W2[(size_t)k * F2 + n];
    }
}

// ---------------- MFMA fp16 GEMM tile + fused alpha dots (head-major alpha out) ----------------
// AF32: A is fp32 (layer 1 reads x directly, converts in-register during staging).
template <bool AF32>
static __device__ void gemm_tile(const _Float16* __restrict__ Ah,
                                 const float* __restrict__ Af,
                                 const _Float16* __restrict__ BT,
                                 _Float16* __restrict__ C,
                                 const float* __restrict__ a_src,
                                 const float* __restrict__ a_dst,
                                 float* __restrict__ as_out,
                                 float* __restrict__ ad_out,
                                 int K, int bmi, int head,
                                 _Float16* As, _Float16* Bs) {
    const int tid = threadIdx.x;
    const int wave = tid >> 6, lane = tid & 63;
    const int q = lane >> 4, ml = lane & 15;
    const int bm = bmi * 64, bn = head * 128;
    const int srow = tid >> 2, scol = (tid & 3) * 8;

    frag_c acc[8];
#pragma unroll
    for (int f = 0; f < 8; f++)
#pragma unroll
        for (int r = 0; r < 4; r++) acc[f][r] = 0.f;

    for (int k0 = 0; k0 < K; k0 += 32) {
        int gm = bm + srow;
        frag_ab av;
        if (gm < Nn) {
            if constexpr (AF32) {
                const float* Ap = Af + (size_t)gm * K + k0 + scol;
                float4 v0 = *(const float4*)Ap;
                float4 v1 = *(const float4*)(Ap + 4);
                av[0] = (_Float16)v0.x; av[1] = (_Float16)v0.y;
                av[2] = (_Float16)v0.z; av[3] = (_Float16)v0.w;
                av[4] = (_Float16)v1.x; av[5] = (_Float16)v1.y;
                av[6] = (_Float16)v1.z; av[7] = (_Float16)v1.w;
            } else {
                av = *(const frag_ab*)(Ah + (size_t)gm * K + k0 + scol);
            }
        } else {
#pragma unroll
            for (int j = 0; j < 8; j++) av[j] = (_Float16)0.f;
        }
        *(frag_ab*)&As[srow * LDK + scol] = av;
        *(frag_ab*)&Bs[srow * LDK + scol] =
            *(const frag_ab*)(BT + (size_t)(bn + srow) * K + k0 + scol);
        *(frag_ab*)&Bs[(64 + srow) * LDK + scol] =
            *(const frag_ab*)(BT + (size_t)(bn + 64 + srow) * K + k0 + scol);
        __syncthreads();
        frag_ab a = *(frag_ab*)&As[(wave * 16 + ml) * LDK + q * 8];
#pragma unroll
        for (int f = 0; f < 8; f++) {
            frag_ab b = *(frag_ab*)&Bs[(f * 16 + ml) * LDK + q * 8];
            acc[f] = __builtin_amdgcn_mfma_f32_16x16x32_f16(a, b, acc[f], 0, 0, 0);
        }
        __syncthreads();
    }
    float asum[4] = {}, dsum[4] = {};
#pragma unroll
    for (int f = 0; f < 8; f++) {
        int cl = f * 16 + ml;
        int col = bn + cl;
        float sa = a_src[head * 128 + cl];
        float da = a_dst[head * 128 + cl];
#pragma unroll
        for (int r = 0; r < 4; r++) {
            int row = bm + wave * 16 + q * 4 + r;
            if (row < Nn) C[(size_t)row * (NH * 128) + col] = (_Float16)acc[f][r];
            asum[r] += acc[f][r] * sa;
            dsum[r] += acc[f][r] * da;
        }
    }
#pragma unroll
    for (int r = 0; r < 4; r++) {
#pragma unroll
        for (int off = 1; off < 16; off <<= 1) {
            asum[r] += __shfl_xor(asum[r], off);
            dsum[r] += __shfl_xor(dsum[r], off);
        }
    }
    if (ml == 0) {
#pragma unroll
        for (int r = 0; r < 4; r++) {
            int row = bm + wave * 16 + q * 4 + r;
            if (row < Nn) {
                as_out[(size_t)head * Nn + row] = asum[r];
                ad_out[(size_t)head * Nn + row] = dsum[r];
            }
        }
    }
}

// XCD-congruent swizzle: bid = m8 + 8*(h + 4*mhi). All 4 heads of A-tile m share
// bid mod 8 (== m mod 8) -> same XCD -> A tile fetched from HBM once, 3x L2 hits.
__global__ __launch_bounds__(256) void gemm1(const float* __restrict__ x,
                                             const _Float16* __restrict__ w1t,
                                             _Float16* __restrict__ hh,
                                             const float* __restrict__ a_src,
                                             const float* __restrict__ a_dst,
                                             float* __restrict__ as_out,
                                             float* __restrict__ ad_out) {
    __shared__ _Float16 As[64 * LDK];
    __shared__ _Float16 Bs[128 * LDK];
    int bid = blockIdx.x;
    int m8 = bid & 7, rest = bid >> 3;
    int h = rest & 3, mhi = rest >> 2;
    int m = mhi * 8 + m8;
    if (m >= MT) return;
    gemm_tile<true>(nullptr, x, w1t, hh, a_src, a_dst, as_out, ad_out, INF_, m, h, As, Bs);
}

__global__ __launch_bounds__(256) void gemm2(const _Float16* __restrict__ aggh,
                                             const _Float16* __restrict__ w2t,
                                             _Float16* __restrict__ hh,
                                             const float* __restrict__ a_src,
                                             const float* __restrict__ a_dst,
                                             float* __restrict__ as_out,
                                             float* __restrict__ ad_out) {
    __shared__ _Float16 As[64 * LDK];
    __shared__ _Float16 Bs[128 * LDK];
    int bid = blockIdx.x;
    int m8 = bid & 7, rest = bid >> 3;
    int h = rest & 3, mhi = rest >> 2;
    int m = mhi * 8 + m8;
    if (m >= MT) return;
    gemm_tile<false>(aggh, nullptr, w2t, hh, a_src, a_dst, as_out, ad_out, F1, m, h, As, Bs);
}

// ---------------- fused softmax + aggregation, layer 1 (head-sliced, round-1 proven) ----------------
__global__ __launch_bounds__(256) void passAB1(const int* __restrict__ counts,
                                               const int* __restrict__ csr,
                                               const float* __restrict__ as,
                                               const float* __restrict__ ad,
                                               const _Float16* __restrict__ hh,
                                               const float* __restrict__ b1,
                                               _Float16* __restrict__ agg) {
    __shared__ int2 ew[16][84];   // stride 84 -> 2-way max bank aliasing (free)
    int head = blockIdx.x & 3;
    int qw = threadIdx.x >> 4;
    int l = threadIdx.x & 15;
    int n = (blockIdx.x >> 2) * 16 + qw;
    int deg = counts[n]; if (deg > STRIDE) deg = STRIDE;
    int pdeg = (deg + 7) & ~7;
    const float* ash = as + (size_t)head * Nn;
    float adh = ad[(size_t)head * Nn + n];
    int base = n * STRIDE;
    float m = -1e30f;
    for (int k = l; k < pdeg; k += 16) {
        int src = 0; float v = -1e30f;
        if (k < deg) {
            src = csr[base + k];
            v = lrelu(ash[src] + adh);
        }
        ew[qw][k] = make_int2(src, __float_as_int(v));
        m = fmaxf(m, v);
    }
    m = fmaxf(m, __shfl_xor(m, 1));
    m = fmaxf(m, __shfl_xor(m, 2));
    m = fmaxf(m, __shfl_xor(m, 4));
    m = fmaxf(m, __shfl_xor(m, 8));
    float s = 0.f;
    for (int k = l; k < pdeg; k += 16) {
        float e = __expf(__int_as_float(ew[qw][k].y) - m);
        ew[qw][k].y = __float_as_int(e);
        s += e;
    }
    s += __shfl_xor(s, 1);
    s += __shfl_xor(s, 2);
    s += __shfl_xor(s, 4);
    s += __shfl_xor(s, 8);
    float inv = 1.f / (s + 1e-16f);
    int c = head * 128 + (l << 3);
    float acc[8] = {};
    for (int kk = 0; kk < pdeg; kk += 8) {
        int2 pj[8];
#pragma unroll
        for (int j = 0; j < 8; j++) pj[j] = ew[qw][kk + j];
#pragma unroll
        for (int j = 0; j < 8; j++) {
            float w = __int_as_float(pj[j].y);
            frag_ab r = *(const frag_ab*)(hh + (size_t)pj[j].x * F1 + c);
#pragma unroll
            for (int u = 0; u < 8; u++) acc[u] = fmaf((float)r[u], w, acc[u]);
        }
    }
    _Float16 oh[8];
#pragma unroll
    for (int j = 0; j < 8; j++)
        oh[j] = (_Float16)fmaxf(acc[j] * inv + b1[c + j], 0.f);
    *(float4*)&agg[(size_t)n * F1 + c] = *(float4*)oh;
}

// ---------------- layer 2: all-heads softmax + aggregation + head-mean + bias -> out ----------------
// One wave per node: lane l -> head h = l>>4, channels 8l..8l+8 (all 512 ch of hh).
// Per-head softmax in aligned 16-lane groups; gathers are 1 KB fully-coalesced lines;
// head-mean via shfl_xor(16,32) in fp32 (kills the reduce4 dispatch + 15 MB tmp traffic).
__global__ __launch_bounds__(256) void passC(const int* __restrict__ counts,
                                             const int* __restrict__ csr,
                                             const float* __restrict__ as,
                                             const float* __restrict__ ad,
                                             const _Float16* __restrict__ hh,
                                             const float* __restrict__ b2,
                                             float* __restrict__ out) {
    __shared__ int   esrc[4][80];        // [wave][k]  (same value written by 16 lanes of head 0)
    __shared__ float ewgt[4][4][80];     // [wave][head][k]
    int w = threadIdx.x >> 6;
    int lane = threadIdx.x & 63;
    int h = lane >> 4, i = lane & 15;
    int n = blockIdx.x * 4 + w;
    int deg = counts[n]; if (deg > STRIDE) deg = STRIDE;
    int pdeg = (deg + 7) & ~7;
    float adh = ad[(size_t)h * Nn + n];
    const float* ash = as + (size_t)h * Nn;
    int base = n * STRIDE;
    float m = -1e30f;
    for (int k = i; k < pdeg; k += 16) {
        int src = 0; float v = -1e30f;
        if (k < deg) {
            src = csr[base + k];
            v = lrelu(ash[src] + adh);
        }
        if (h == 0) esrc[w][k] = src;
        ewgt[w][h][k] = v;
        m = fmaxf(m, v);
    }
    m = fmaxf(m, __shfl_xor(m, 1));
    m = fmaxf(m, __shfl_xor(m, 2));
    m = fmaxf(m, __shfl_xor(m, 4));
    m = fmaxf(m, __shfl_xor(m, 8));
    float s = 0.f;
    for (int k = i; k < pdeg; k += 16) {
        float e = __expf(ewgt[w][h][k] - m);
        ewgt[w][h][k] = e;
        s += e;
    }
    s += __shfl_xor(s, 1);
    s += __shfl_xor(s, 2);
    s += __shfl_xor(s, 4);
    s += __shfl_xor(s, 8);
    float scale = 0.25f / (s + 1e-16f);
    // wave-private LDS (no cross-wave sharing) -> in-order wave mem ops, no barrier needed
    int c = lane << 3;
    float acc[8] = {};
    for (int kk = 0; kk < pdeg; kk += 8) {
        int s8[8]; float w8[8];
#pragma unroll
        for (int j = 0; j < 8; j++) { s8[j] = esrc[w][kk + j]; w8[j] = ewgt[w][h][kk + j]; }
#pragma unroll
        for (int j = 0; j < 8; j++) {
            frag_ab r = *(const frag_ab*)(hh + (size_t)s8[j] * F2 + c);
#pragma unroll
            for (int u = 0; u < 8; u++) acc[u] = fmaf((float)r[u], w8[j], acc[u]);
        }
    }
#pragma unroll
    for (int u = 0; u < 8; u++) {
        acc[u] *= scale;
        acc[u] += __shfl_xor(acc[u], 16);
        acc[u] += __shfl_xor(acc[u], 32);
    }
    if (h == 0) {
        float o[8];
#pragma unroll
        for (int j = 0; j < 8; j++) o[j] = acc[j] + b2[(i << 3) + j];
        *(float4*)&out[(size_t)n * OUTC + (i << 3)]     = *(float4*)&o[0];
        *(float4*)&out[(size_t)n * OUTC + (i << 3) + 4] = *(float4*)&o[4];
    }
}

extern "C" void kernel_launch(void* const* d_in, const int* in_sizes, int n_in,
                              void* d_out, int out_size, void* d_ws, size_t ws_size,
                              hipStream_t stream) {
    const float* x      = (const float*)d_in[0];
    const int*   ei     = (const int*)d_in[1];
    const float* W1     = (const float*)d_in[2];
    const float* a_src1 = (const float*)d_in[3];
    const float* a_dst1 = (const float*)d_in[4];
    const float* b1     = (const float*)d_in[5];
    const float* W2     = (const float*)d_in[6];
    const float* a_src2 = (const float*)d_in[7];
    const float* a_dst2 = (const float*)d_in[8];
    const float* b2     = (const float*)d_in[9];
    float* out = (float*)d_out;

    char* w = (char*)d_ws;
    _Float16* hh   = (_Float16*)w; w += (size_t)Nn * F1 * 2;
    _Float16* aggh = (_Float16*)w; w += (size_t)Nn * F1 * 2;
    _Float16* w1t  = (_Float16*)w; w += (size_t)F1 * INF_ * 2;
    _Float16* w2t  = (_Float16*)w; w += (size_t)F2 * F1 * 2;
    float* as1     = (float*)w;    w += (size_t)NH * Nn * 4;
    float* ad1     = (float*)w;    w += (size_t)NH * Nn * 4;
    float* as2     = (float*)w;    w += (size_t)NH * Nn * 4;
    float* ad2     = (float*)w;    w += (size_t)NH * Nn * 4;
    int* csr       = (int*)w;      w += (size_t)Nn * STRIDE * 4;
    int* counts    = (int*)w;      w += (size_t)Nn * 4;

    (void)hipMemsetAsync(counts, 0, Nn * sizeof(int), stream);
    prep<<<SC_BLOCKS + TW1_BLOCKS + TW2_BLOCKS, 256, 0, stream>>>(
        ei, counts, csr, W1, W2, w1t, w2t);

    // Layer 1
    gemm1<<<GEMM_GRID, 256, 0, stream>>>(x, w1t, hh, a_src1, a_dst1, as1, ad1);
    passAB1<<<(Nn / 16) * NH, 256, 0, stream>>>(counts, csr, as1, ad1, hh, b1, aggh);

    // Layer 2
    gemm2<<<GEMM_GRID, 256, 0, stream>>>(aggh, w2t, hh, a_src2, a_dst2, as2, ad2);
    passC<<<Nn / 4, 256, 0, stream>>>(counts, csr, as2, ad2, hh, b2, out);
}